// Round 28
// baseline (62.257 us; speedup 1.0000x reference)
//
#include <hip/hip_runtime.h>
#include <hip/hip_bf16.h>

#define STATE 16
#define DNA_C 4
#define HID   128
#define FAN1  52
#define HH    256
#define WW    256
#define HW    (HH * WW)

typedef unsigned short u16;
typedef unsigned int   u32;
typedef short bf8 __attribute__((ext_vector_type(8)));
typedef float f32x4 __attribute__((ext_vector_type(4)));
typedef float f32x2 __attribute__((ext_vector_type(2)));

typedef __attribute__((address_space(1))) const void gv_t;   // global
typedef __attribute__((address_space(3))) void lv_t;         // LDS

__device__ __forceinline__ u32 pk(float a, float b) {
    __hip_bfloat162 t = __float22bfloat162_rn(make_float2(a, b));  // v_cvt_pk_bf16_f32
    union { __hip_bfloat162 h; u32 u; } c; c.h = t; return c.u;
}
__device__ __forceinline__ u16 f2bf(float f) {
    union { __hip_bfloat16 h; u16 u; } c; c.h = __float2bfloat16(f); return c.u;
}

// w1 [128][52] f32 -> bf16 [128][64], DOUBLY permuted (identical to rounds 23-27):
//  * k-permutation: knew = 16w + t: t0-3 = x ch 4w+t, t4-7 = gx, t8-11 = gy,
//    t==12 = dna ch w (one dna channel per wave), t13-15 = pad.
//  * M-permutation (r13): physical row p=16m+4g+r holds true hidden
//    H = 32(m>>1)+8g+4(m&1)+r -> L1 D-fragment IS the L2 B-fragment (register-only L2).
// w2 [16][128] -> bf16 plain.
__global__ void prep_weights(const float* __restrict__ w1, const float* __restrict__ w2,
                             u16* __restrict__ wb) {
    int i = blockIdx.x * 256 + threadIdx.x;   // 0..10239
    if (i < 128 * 64) {
        int p = i >> 6, knew = i & 63;
        int m = p >> 4, g = (p >> 2) & 3, r = p & 3;
        int hrow = 32 * (m >> 1) + 8 * g + 4 * (m & 1) + r;   // true hidden row at physical p
        int w = knew >> 4, t = knew & 15;
        float v = 0.f;
        if (t < 4)        v = w1[hrow * FAN1 + 4 * w + t];
        else if (t < 8)   v = w1[hrow * FAN1 + 16 + 4 * w + (t - 4)];
        else if (t < 12)  v = w1[hrow * FAN1 + 32 + 4 * w + (t - 8)];
        else if (t == 12) v = w1[hrow * FAN1 + 48 + w];        // dna ch w in wave w's chunk
        wb[i] = f2bf(v);
    } else if (i < 128 * 64 + 16 * 128) {
        wb[i] = f2bf(w2[i - 128 * 64]);
    }
}

__global__ __launch_bounds__(256, 2) void update_net28(
    const float* __restrict__ x,    // [B,16,256,256]
    const float* __restrict__ dna,  // [B,4,256,256]
    const u16*   __restrict__ wb,   // permuted bf16 w1 [128][64], w2 [16][128]
    float* __restrict__ out,        // [B,16,256,256]
    int nrows)                      // B*256
{
    // Half-row software pipeline over the r24 ring structure:
    //  * ring is per-wave-private BY CHANNEL (wave wv stages and reads only ch 4wv..4wv+3)
    //    -> ring recycling needs NO cross-wave sync; only feat is cross-wave.
    //  * feat double-buffered at half-row granularity (2 x 16 KB); region s:
    //      {stage(y+1) if h==0 ; MLP(half s-1, buf (s-1)&1) ; vmcnt gate ;
    //       feature(half s, buf s&1)} ; __syncthreads
    //    MLP and feature touch DISJOINT buffers -> independent MFMA/VALU/DS per region.
    //  * vmcnt(8) gate: 8 younger out-stores outstanding; waits exactly the 4 stage loads
    //    (in-order FIFO vmcnt).
    __shared__ __align__(16) float raw_lds[3][STATE * WW];   // 48 KB
    __shared__ __align__(16) u16 featA[128 * 64];            // 16 KB (h==0)
    __shared__ __align__(16) u16 featB[128 * 64];            // 16 KB (h==1)

    const int tid  = threadIdx.x;
    const int lane = tid & 63;
    const int wv   = tid >> 6;
    const int fj   = lane & 15;   // B-col / D-col (px in group), A-row
    const int fg   = lane >> 4;   // k-group (A/B), state-group (D)
    const int px0g = lane * 4;    // staging column base

    // ---- weight fragments ONCE per block (register-resident, r13 layout) ----
    const u16* w1b = wb;             // [128][64] doubly permuted
    const u16* w2b = wb + 128 * 64;  // [16][128]
    bf8 a1[8][2];
    #pragma unroll
    for (int m = 0; m < 8; ++m) {
        #pragma unroll
        for (int kt = 0; kt < 2; ++kt)
            a1[m][kt] = *(const bf8*)&w1b[(16 * m + fj) * 64 + 32 * kt + 8 * fg];
    }
    bf8 a2[4];
    #pragma unroll
    for (int kt = 0; kt < 4; ++kt)
        a2[kt] = *(const bf8*)&w2b[fj * 128 + 32 * kt + 8 * fg];

    const f32x4 z0 = {0.f, 0.f, 0.f, 0.f};   // shared MFMA C-in (read-only)

    // ---- chunking: 512 blocks x 8 rows, chunks nest inside batches (8 | 256) ----
    const int q  = nrows / gridDim.x;        // 8
    const int start = blockIdx.x * q;
    const int b  = start >> 8;               // constant over the chunk
    const int y0 = start & 255;

    auto stage_row = [&](int yy, int slot) {
        const float* g = x + (((size_t)(b * STATE + 4 * wv)) * HH + yy) * WW + px0g;
        float* l = &raw_lds[slot][(4 * wv) * WW];
        #pragma unroll
        for (int c = 0; c < 4; ++c)
            __builtin_amdgcn_global_load_lds((gv_t*)(g + (size_t)c * HW),
                                             (lv_t*)(l + c * WW), 16, 0, 0);
    };

    // ---- feature for one 128-px half-row: 2 px/lane, wave's 4 channels ----
    auto feature_half = [&](int y, int h, u16* fbuf) {
        const bool ht = (y > 0), hb = (y < HH - 1);
        const int sm = y % 3, st = (y + 2) % 3, sb = (y + 1) % 3;
        const int px = 128 * h + 2 * lane;                   // global column of the pair
        const f32x2 dn2 = *(const f32x2*)(dna + (((size_t)(b * DNA_C + wv)) * HH + y) * WW + px);

        float sx[4][2], gx[4][2], gy[4][2];
        #pragma unroll
        for (int c = 0; c < 4; ++c) {
            const float* rm = &raw_lds[sm][(4 * wv + c) * WW];
            const float* rt = &raw_lds[st][(4 * wv + c) * WW];
            const float* rb = &raw_lds[sb][(4 * wv + c) * WW];
            f32x2 m2 = *(const f32x2*)(rm + px);
            f32x2 t2 = {0.f, 0.f}, b2 = {0.f, 0.f};
            if (ht) t2 = *(const f32x2*)(rt + px);
            if (hb) b2 = *(const f32x2*)(rb + px);
            const float cs0 = fmaf(2.f, m2[0], t2[0] + b2[0]);
            const float cs1 = fmaf(2.f, m2[1], t2[1] + b2[1]);
            const float d0  = b2[0] - t2[0];
            const float d1  = b2[1] - t2[1];
            // half-edge columns come from the ring (full row resident); image borders zero
            float csE = 0.f, dE = 0.f;
            const bool lo = (lane == 0), hi = (lane == 63);
            const bool useE = lo ? (h == 1) : (hi ? (h == 0) : false);
            if (useE) {
                const int ec = lo ? 127 : 128;               // col 128h-1 / 128h+128
                const float mE = rm[ec];
                const float tE = ht ? rt[ec] : 0.f;
                const float bE = hb ? rb[ec] : 0.f;
                csE = fmaf(2.f, mE, tE + bE);
                dE  = bE - tE;
            }
            float csL = __shfl_up(cs1, 1);
            float csR = __shfl_down(cs0, 1);
            float dL  = __shfl_up(d1, 1);
            float dR  = __shfl_down(d0, 1);
            if (lo) { csL = csE; dL = dE; }
            if (hi) { csR = csE; dR = dE; }
            sx[c][0] = m2[0];          sx[c][1] = m2[1];
            gx[c][0] = cs1 - csL;      gx[c][1] = csR - cs0;
            gy[c][0] = fmaf(2.f, d0, dL + d1);
            gy[c][1] = fmaf(2.f, d1, d0 + dR);
        }
        const int sW = (lane >> 1) & 7;                      // (lpx>>2)&7, same for both px
        #pragma unroll
        for (int i = 0; i < 2; ++i) {
            const int lpx = 2 * lane + i;                    // local px in the half
            u16* rowp = &fbuf[lpx * 64];
            uint4 c0 = make_uint4(pk(sx[0][i], sx[1][i]), pk(sx[2][i], sx[3][i]),
                                  pk(gx[0][i], gx[1][i]), pk(gx[2][i], gx[3][i]));
            uint4 c1 = make_uint4(pk(gy[0][i], gy[1][i]), pk(gy[2][i], gy[3][i]),
                                  pk(dn2[i], 0.f), 0u);
            *(uint4*)&rowp[8 * ((2 * wv)     ^ sW)] = c0;    // knew 16wv..+7  : x | gx
            *(uint4*)&rowp[8 * ((2 * wv + 1) ^ sW)] = c1;    // knew +8..15 : gy | dna(wv) | pad
        }
    };

    // ---- MLP for one 128-px half-row: wave covers px [32wv, 32wv+32), 2 groups ----
    auto mlp_half = [&](int y, int h, const u16* fbuf) {
        #pragma unroll
        for (int g2 = 0; g2 < 2; ++g2) {
            const int r  = 32 * wv + 16 * g2 + fj;           // local px row
            const int sg = (r >> 2) & 7;
            bf8 b0 = *(const bf8*)&fbuf[r * 64 + 8 * ((0 + fg) ^ sg)];
            bf8 b1 = *(const bf8*)&fbuf[r * 64 + 8 * ((4 + fg) ^ sg)];

            u32 w[8][2];
            #pragma unroll
            for (int mh = 0; mh < 2; ++mh) {
                f32x4 hc[4];
                #pragma unroll
                for (int mm = 0; mm < 4; ++mm) {
                    const int m = mh * 4 + mm;
                    f32x4 z = __builtin_amdgcn_mfma_f32_16x16x32_bf16(a1[m][0], b0, z0, 0, 0, 0);
                    hc[mm] = __builtin_amdgcn_mfma_f32_16x16x32_bf16(a1[m][1], b1, z, 0, 0, 0);
                }
                #pragma unroll
                for (int mm = 0; mm < 4; ++mm) {
                    const int m = mh * 4 + mm;
                    w[m][0] = pk(fmaxf(hc[mm][0], 0.f), fmaxf(hc[mm][1], 0.f));
                    w[m][1] = pk(fmaxf(hc[mm][2], 0.f), fmaxf(hc[mm][3], 0.f));
                }
            }
            f32x4 uacc;
            #pragma unroll
            for (int kt = 0; kt < 4; ++kt) {
                union { u32 u[4]; bf8 v; } bb;
                bb.u[0] = w[2 * kt][0];
                bb.u[1] = w[2 * kt][1];
                bb.u[2] = w[2 * kt + 1][0];
                bb.u[3] = w[2 * kt + 1][1];
                uacc = __builtin_amdgcn_mfma_f32_16x16x32_bf16(a2[kt], bb.v,
                                                               (kt == 0) ? z0 : uacc, 0, 0, 0);
            }
            const int xo = 128 * h + 32 * wv + 16 * g2 + fj;
            float* po = out + (((size_t)(b * STATE + 4 * fg)) * HH + y) * WW + xo;
            #pragma unroll
            for (int rr = 0; rr < 4; ++rr)
                po[(size_t)rr * HW] = uacc[rr];
        }
    };

    // ---- prologue: stage the first row's stencil ----
    if (y0 > 0) stage_row(y0 - 1, (y0 - 1) % 3);
    stage_row(y0, y0 % 3);
    stage_row(y0 + 1, (y0 + 1) % 3);         // y0+1 <= 255 (chunk nests in batch)
    asm volatile("s_waitcnt vmcnt(0)" ::: "memory");
    __builtin_amdgcn_sched_barrier(0);
    __syncthreads();

    const int S = 2 * q;                      // 16 half-row steps
    for (int s = 0; s < S; ++s) {
        const int y = y0 + (s >> 1);
        const int h = s & 1;
        const bool do_stage = (h == 0) && (s > 0) && (y + 1 <= HH - 1);
        if (do_stage)
            stage_row(y + 1, (y + 1) % 3);    // slot's readers finished by last barrier

        if (s > 0) {
            const int yp = y0 + ((s - 1) >> 1);
            const int hp = (s - 1) & 1;
            mlp_half(yp, hp, hp ? featB : featA);   // reads OLD buffer
        }

        if (do_stage) {
            // wait the 4 stage loads only: the 8 out-stores above are younger (FIFO vmcnt)
            __builtin_amdgcn_sched_barrier(0);
            asm volatile("s_waitcnt vmcnt(8)" ::: "memory");
            __builtin_amdgcn_sched_barrier(0);
        }

        feature_half(y, h, h ? featB : featA);      // writes NEW buffer

        __syncthreads();   // feat visibility + all LDS reads of old buffers complete
    }
    mlp_half(y0 + q - 1, 1, featB);                 // epilogue: last half's MLP
}

extern "C" void kernel_launch(void* const* d_in, const int* in_sizes, int n_in,
                              void* d_out, int out_size, void* d_ws, size_t ws_size,
                              hipStream_t stream) {
    const float* x   = (const float*)d_in[0];
    const float* dna = (const float*)d_in[1];
    const float* w1  = (const float*)d_in[2];
    const float* w2  = (const float*)d_in[3];
    float* out = (float*)d_out;
    u16* wb = (u16*)d_ws;   // 10240 u16 = 20 KB

    prep_weights<<<dim3(40), dim3(256), 0, stream>>>(w1, w2, wb);

    const int B = in_sizes[0] / (STATE * HH * WW);   // 16
    const int nrows = B * HH;                        // 4096
    const int grid = 512;                            // 2 blocks/CU, 8 rows each, 8 | 256
    update_net28<<<dim3(grid), dim3(256), 0, stream>>>(x, dna, wb, out, nrows);
}

// Round 29
// 47.524 us; speedup vs baseline: 1.3100x; 1.3100x over previous
//
#include <hip/hip_runtime.h>
#include <hip/hip_bf16.h>

#define STATE 16
#define DNA_C 4
#define HID   128
#define FAN1  52
#define HH    256
#define WW    256
#define HW    (HH * WW)

typedef unsigned short u16;
typedef unsigned int   u32;
typedef short bf8 __attribute__((ext_vector_type(8)));
typedef float f32x4 __attribute__((ext_vector_type(4)));

typedef __attribute__((address_space(1))) const void gv_t;   // global
typedef __attribute__((address_space(3))) void lv_t;         // LDS

// HW packed f32->bf16 (RTNE): one v_cvt_pk_bf16_f32. The HIP header path
// (__float22bfloat162_rn) may lower to a multi-op software RTNE sequence —
// this asm guarantees the single-instruction form (T12 recipe).
__device__ __forceinline__ u32 pk(float a, float b) {
    u32 r;
    asm("v_cvt_pk_bf16_f32 %0, %1, %2" : "=v"(r) : "v"(a), "v"(b));
    return r;
}
__device__ __forceinline__ u16 f2bf(float f) {
    union { __hip_bfloat16 h; u16 u; } c; c.h = __float2bfloat16(f); return c.u;
}

// chunk swizzle: distinct mod 8 over 8 consecutive px (conflict-free MLP reads)
// AND over the write side's px=4*lane+i stride pattern (conflict-free writes).
#define FSWZ(px) ((((px) >> 2) ^ (2 * (px))) & 7)

// w1 [128][52] f32 -> bf16 [128][64], DOUBLY permuted (identical to rounds 23/24):
//  * k-permutation: knew = 16w + t: t0-3 = x ch 4w+t, t4-7 = gx, t8-11 = gy,
//    t==12 = dna ch w (one dna channel per wave), t13-15 = pad.
//  * M-permutation (r13): physical row p=16m+4g+r holds true hidden
//    H = 32(m>>1)+8g+4(m&1)+r -> L1 D-fragment IS the L2 B-fragment (register-only L2).
// w2 [16][128] -> bf16 plain.
__global__ void prep_weights(const float* __restrict__ w1, const float* __restrict__ w2,
                             u16* __restrict__ wb) {
    int i = blockIdx.x * 256 + threadIdx.x;   // 0..10239
    if (i < 128 * 64) {
        int p = i >> 6, knew = i & 63;
        int m = p >> 4, g = (p >> 2) & 3, r = p & 3;
        int hrow = 32 * (m >> 1) + 8 * g + 4 * (m & 1) + r;   // true hidden row at physical p
        int w = knew >> 4, t = knew & 15;
        float v = 0.f;
        if (t < 4)        v = w1[hrow * FAN1 + 4 * w + t];
        else if (t < 8)   v = w1[hrow * FAN1 + 16 + 4 * w + (t - 4)];
        else if (t < 12)  v = w1[hrow * FAN1 + 32 + 4 * w + (t - 8)];
        else if (t == 12) v = w1[hrow * FAN1 + 48 + w];        // dna ch w in wave w's chunk
        wb[i] = f2bf(v);
    } else if (i < 128 * 64 + 16 * 128) {
        wb[i] = f2bf(w2[i - 128 * 64]);
    }
}

__global__ __launch_bounds__(256, 2) void update_net29(
    const float* __restrict__ x,    // [B,16,256,256]
    const float* __restrict__ dna,  // [B,4,256,256]
    const u16*   __restrict__ wb,   // permuted bf16 w1 [128][64], w2 [16][128]
    float* __restrict__ out,        // [B,16,256,256]
    int nrows)                      // B*256
{
    // Round-24 champion structure with two instruction-level fixes:
    //  * pk() = single v_cvt_pk_bf16_f32 via inline asm (suspected software-RTNE before)
    //  * FSWZ chunk swizzle: conflict-free feat writes AND MLP b128 reads
    __shared__ __align__(16) float raw_lds[3][STATE * WW];   // 48 KB
    __shared__ __align__(16) u16 feat_lds[256 * 64];         // 32 KB

    const int tid  = threadIdx.x;
    const int lane = tid & 63;
    const int wv   = tid >> 6;
    const int fj   = lane & 15;   // A-row / B-col / D-col
    const int fg   = lane >> 4;   // k-group (A/B), row-group (D)
    const int px0  = lane * 4;

    // ---- weight fragments ONCE per block (register-resident, r13 layout) ----
    const u16* w1b = wb;             // [128][64] doubly permuted
    const u16* w2b = wb + 128 * 64;  // [16][128]
    bf8 a1[8][2];
    #pragma unroll
    for (int m = 0; m < 8; ++m) {
        #pragma unroll
        for (int kt = 0; kt < 2; ++kt)
            a1[m][kt] = *(const bf8*)&w1b[(16 * m + fj) * 64 + 32 * kt + 8 * fg];
    }
    bf8 a2[4];
    #pragma unroll
    for (int kt = 0; kt < 4; ++kt)
        a2[kt] = *(const bf8*)&w2b[fj * 128 + 32 * kt + 8 * fg];

    const f32x4 z0 = {0.f, 0.f, 0.f, 0.f};   // shared MFMA C-in (read-only)

    // ---- chunking: 512 blocks x 8 rows, chunks nest inside batches (8 | 256) ----
    const int q  = nrows / gridDim.x;        // 8
    const int start = blockIdx.x * q;
    const int b  = start >> 8;               // constant over the chunk
    const int y0 = start & 255;

    // stage this wave's 4 channels of x row (b,yy) into ring slot (async, no regs)
    auto stage_row = [&](int yy, int slot) {
        const float* g = x + (((size_t)(b * STATE + 4 * wv)) * HH + yy) * WW + px0;
        float* l = &raw_lds[slot][(4 * wv) * WW];
        #pragma unroll
        for (int c = 0; c < 4; ++c)
            __builtin_amdgcn_global_load_lds((gv_t*)(g + (size_t)c * HW),
                                             (lv_t*)(l + c * WW), 16, 0, 0);
    };

    // ---- prologue: stencil rows for the first row of the chunk ----
    if (y0 > 0) stage_row(y0 - 1, (y0 - 1) % 3);
    stage_row(y0, y0 % 3);
    stage_row(y0 + 1, (y0 + 1) % 3);         // y0+1 <= 255 always (chunk nests in batch)
    asm volatile("s_waitcnt vmcnt(0)" ::: "memory");
    __builtin_amdgcn_sched_barrier(0);

    for (int it = 0; it < q; ++it) {
        const int y = y0 + it;
        const bool ht = (y > 0), hb = (y < HH - 1);
        const int sm = y % 3, st3 = (y + 2) % 3, sb = (y + 1) % 3;   // m / t / b slots

        // ---- feature phase: Sobel from the LDS ring; dna direct (1 load, balanced) ----
        {
            const f32x4 dnv = *(const f32x4*)(dna + (((size_t)(b * DNA_C + wv)) * HH + y) * WW + px0);
            const float* rm_ = &raw_lds[sm][(4 * wv) * WW + px0];
            const float* rt_ = &raw_lds[st3][(4 * wv) * WW + px0];
            const float* rb_ = &raw_lds[sb][(4 * wv) * WW + px0];

            f32x4 xm[4], gx[4], gy[4];
            #pragma unroll
            for (int c = 0; c < 4; ++c) {
                f32x4 m4 = *(const f32x4*)(rm_ + c * WW);
                f32x4 t4 = {0.f,0.f,0.f,0.f}, b4 = {0.f,0.f,0.f,0.f};
                if (ht) t4 = *(const f32x4*)(rt_ + c * WW);
                if (hb) b4 = *(const f32x4*)(rb_ + c * WW);
                f32x4 cs, d;
                #pragma unroll
                for (int i = 0; i < 4; ++i) {
                    cs[i] = fmaf(2.f, m4[i], t4[i] + b4[i]);   // colsum t+2m+b
                    d[i]  = b4[i] - t4[i];
                }
                float csL = __shfl_up(cs[3], 1);
                float csR = __shfl_down(cs[0], 1);
                float dL  = __shfl_up(d[3], 1);
                float dR  = __shfl_down(d[0], 1);
                if (lane == 0)  { csL = 0.f; dL = 0.f; }       // image left border
                if (lane == 63) { csR = 0.f; dR = 0.f; }       // image right border
                xm[c] = m4;
                gx[c][0] = cs[1] - csL;   gx[c][1] = cs[2] - cs[0];
                gx[c][2] = cs[3] - cs[1]; gx[c][3] = csR - cs[2];
                gy[c][0] = fmaf(2.f, d[0], dL + d[1]);
                gy[c][1] = fmaf(2.f, d[1], d[0] + d[2]);
                gy[c][2] = fmaf(2.f, d[2], d[1] + d[3]);
                gy[c][3] = fmaf(2.f, d[3], d[2] + dR);
            }

            #pragma unroll
            for (int i = 0; i < 4; ++i) {
                const int px = px0 + i;
                const int s = FSWZ(px);
                u16* rowp = &feat_lds[px * 64];
                uint4 c0 = make_uint4(pk(xm[0][i], xm[1][i]), pk(xm[2][i], xm[3][i]),
                                      pk(gx[0][i], gx[1][i]), pk(gx[2][i], gx[3][i]));
                uint4 c1 = make_uint4(pk(gy[0][i], gy[1][i]), pk(gy[2][i], gy[3][i]),
                                      pk(dnv[i], 0.f), 0u);
                *(uint4*)&rowp[8 * ((2 * wv)     ^ s)] = c0;   // knew 16wv..+7  : x | gx
                *(uint4*)&rowp[8 * ((2 * wv + 1) ^ s)] = c1;   // knew +8..15 : gy | dna(wv) | pad
            }
        }

        __syncthreads();   // feature phase is cross-wave (drains vmcnt too)

        // ---- prefetch next stencil row into the retired t-slot, under the MLP ----
        if (it + 1 < q && y + 2 <= HH - 1)
            stage_row(y + 2, (y + 2) % 3);
        __builtin_amdgcn_sched_barrier(0);   // pin stage issue before the MFMA cluster

        #pragma unroll
        for (int g4 = 0; g4 < 4; ++g4) {
            const int r  = wv * 64 + g4 * 16 + fj;
            const int sg = FSWZ(r);
            bf8 b0 = *(const bf8*)&feat_lds[r * 64 + 8 * ((0 + fg) ^ sg)];
            bf8 b1 = *(const bf8*)&feat_lds[r * 64 + 8 * ((4 + fg) ^ sg)];

            // ---- layer 1 in two m-halves; shared z0 as C-in ----
            u32 w[8][2];
            #pragma unroll
            for (int mh = 0; mh < 2; ++mh) {
                f32x4 hc[4];
                #pragma unroll
                for (int mm = 0; mm < 4; ++mm) {
                    const int m = mh * 4 + mm;
                    f32x4 z = __builtin_amdgcn_mfma_f32_16x16x32_bf16(a1[m][0], b0, z0, 0, 0, 0);
                    hc[mm] = __builtin_amdgcn_mfma_f32_16x16x32_bf16(a1[m][1], b1, z, 0, 0, 0);
                }
                #pragma unroll
                for (int mm = 0; mm < 4; ++mm) {
                    const int m = mh * 4 + mm;
                    w[m][0] = pk(fmaxf(hc[mm][0], 0.f), fmaxf(hc[mm][1], 0.f));
                    w[m][1] = pk(fmaxf(hc[mm][2], 0.f), fmaxf(hc[mm][3], 0.f));
                }
            }

            // ---- layer 2: B-fragment from the lane's OWN words (register-only, r13) ----
            f32x4 uacc;
            #pragma unroll
            for (int kt = 0; kt < 4; ++kt) {
                union { u32 u[4]; bf8 v; } bb;
                bb.u[0] = w[2 * kt][0];
                bb.u[1] = w[2 * kt][1];
                bb.u[2] = w[2 * kt + 1][0];
                bb.u[3] = w[2 * kt + 1][1];
                uacc = __builtin_amdgcn_mfma_f32_16x16x32_bf16(a2[kt], bb.v,
                                                               (kt == 0) ? z0 : uacc, 0, 0, 0);
            }

            const int xo = wv * 64 + g4 * 16 + fj;
            float* po = out + (((size_t)(b * STATE + 4 * fg)) * HH + y) * WW + xo;
            #pragma unroll
            for (int rr2 = 0; rr2 < 4; ++rr2)
                po[(size_t)rr2 * HW] = uacc[rr2];
        }

        __syncthreads();   // MLP reads done; drains vmcnt -> staged row ready for next it
    }
}

extern "C" void kernel_launch(void* const* d_in, const int* in_sizes, int n_in,
                              void* d_out, int out_size, void* d_ws, size_t ws_size,
                              hipStream_t stream) {
    const float* x   = (const float*)d_in[0];
    const float* dna = (const float*)d_in[1];
    const float* w1  = (const float*)d_in[2];
    const float* w2  = (const float*)d_in[3];
    float* out = (float*)d_out;
    u16* wb = (u16*)d_ws;   // 10240 u16 = 20 KB

    prep_weights<<<dim3(40), dim3(256), 0, stream>>>(w1, w2, wb);

    const int B = in_sizes[0] / (STATE * HH * WW);   // 16
    const int nrows = B * HH;                        // 4096
    const int grid = 512;                            // 2 blocks/CU, 8 rows each, 8 | 256
    update_net29<<<dim3(grid), dim3(256), 0, stream>>>(x, dna, wb, out, nrows);
}